// Round 5
// baseline (407.834 us; speedup 1.0000x reference)
//
#include <hip/hip_runtime.h>
#include <hip/hip_bf16.h>
#include <float.h>

typedef _Float16 f16;
typedef __attribute__((ext_vector_type(8))) _Float16 half8;
typedef __attribute__((ext_vector_type(4))) float floatx4;
typedef unsigned short u16;
typedef unsigned int u32;

// Problem constants
#define DIM   128
#define HW    4096
#define NPOS  131072
#define K     512
#define ZSTRIDE_B 524288

// Output layout (floats)
#define Q_OFF     0
#define LOSS_OFF  16777216
#define IDX_OFF   16777217
#define NEMB_OFF  16908289
#define NCS_OFF   16973825
#define NEA_OFF   16974337

// Q-region scratch (consumed before k_q overwrites it)
#define QS_PART   0           // 512 blocks x 4096 floats = 8 MB
#define QS_CNT    2097152     // 32 x 512 floats

union U4H8 { uint4 u; half8 h; };

// ---------------------------------------------------------------------------
// k_prep: split codebook into f16 hi/lo, (nc,dc)-tiled: tile t = nc*4+dc holds
// 256 codes x 32 dims row-major (64 B rows).
__global__ __launch_bounds__(256) void k_prep(const float* __restrict__ emb,
                                              u16* __restrict__ ehi,
                                              u16* __restrict__ elo) {
    int lin = blockIdx.x * 256 + threadIdx.x;   // 65536
    int d = lin >> 9, k = lin & 511;
    float v = emb[lin];                          // coalesced
    f16 h = (f16)v;
    f16 l = (f16)(v - (float)h);
    int tile = ((k >> 8) << 2) + (d >> 5);       // nc*4 + dc
    int idx = (tile << 13) + ((k & 255) << 5) + (d & 31);
    union { f16 f; u16 u; } uh, ul; uh.f = h; ul.f = l;
    ehi[idx] = uh.u;
    elo[idx] = ul.u;
}

// ---------------------------------------------------------------------------
// k_e2: per-code squared norms, 2 blocks x 256 threads (ILP via unroll).
__global__ __launch_bounds__(256) void k_e2(const float* __restrict__ emb,
                                            float* __restrict__ e2) {
    int k = blockIdx.x * 256 + threadIdx.x;
    float s = 0.f;
    #pragma unroll 8
    for (int d = 0; d < DIM; ++d) {
        float v = emb[d * K + k];
        s = fmaf(v, v, s);
    }
    e2[k] = s;
}

// ---------------------------------------------------------------------------
// k_assign v3: 64 pos/block, 512 codes, D=128, 3-pass f16-split MFMA.
// B fragments load DIRECTLY from the tiled global codebook (L2-resident,
// each wave load tiles a contiguous 1 KB). xs via ds_write_b128 (bank-clean).
// No barriers in the K-loop, no es LDS, no launch_bounds VGPR clamp.
__global__ __launch_bounds__(256) void k_assign(const float* __restrict__ z,
                                                const uint4* __restrict__ gh4,
                                                const uint4* __restrict__ gl4,
                                                const float* __restrict__ e2,
                                                float* __restrict__ out) {
    __shared__ __align__(16) char smem[32768];
    f16* xs_h = (f16*)smem;                 // 64 pos x 128 d, swizzled (16 KB)
    f16* xs_l = (f16*)(smem + 16384);

    const int tid  = threadIdx.x;
    const int lane = tid & 63;
    const int wv   = tid >> 6;
    const int n0   = blockIdx.x * 64;
    const int b    = n0 >> 12;
    const int hw0  = n0 & 4095;
    const float* zb = z + b * ZSTRIDE_B + hw0;
    const int l15  = lane & 15;
    const int quad = lane >> 4;

    // ---- stage X split: thread handles 8 dims x 1 pos -> one b128 write each
    #pragma unroll
    for (int it = 0; it < 4; ++it) {
        int c8 = wv + it * 4;          // 8-dim chunk 0..15
        int i  = lane;                 // position (lanes consecutive -> coalesced)
        float v[8];
        #pragma unroll
        for (int j = 0; j < 8; ++j) v[j] = zb[(c8 * 8 + j) * HW + i];
        half8 h, l;
        #pragma unroll
        for (int j = 0; j < 8; ++j) {
            f16 hh = (f16)v[j];
            h[j] = hh;
            l[j] = (f16)(v[j] - (float)hh);
        }
        int cc = c8 ^ (i & 7);         // XOR chunk swizzle
        *(half8*)&xs_h[i * 128 + cc * 8] = h;
        *(half8*)&xs_l[i * 128 + cc * 8] = l;
    }
    __syncthreads();

    float bestD[4][4];
    int   bestI[4][4];
    #pragma unroll
    for (int t = 0; t < 4; ++t)
        #pragma unroll
        for (int r = 0; r < 4; ++r) { bestD[t][r] = FLT_MAX; bestI[t][r] = 0x7fffffff; }

    for (int nc = 0; nc < 2; ++nc) {
        floatx4 acc[4][4];
        #pragma unroll
        for (int t = 0; t < 4; ++t)
            #pragma unroll
            for (int g = 0; g < 4; ++g) acc[t][g] = (floatx4){0.f, 0.f, 0.f, 0.f};

        for (int dc = 0; dc < 4; ++dc) {
            // A fragments from LDS: A[m = t*16+l15][k = quad*8+j]
            half8 ah[4], al[4];
            #pragma unroll
            for (int t = 0; t < 4; ++t) {
                int i = t * 16 + l15;
                int cc = (dc * 4 + quad) ^ (i & 7);
                ah[t] = ((const half8*)xs_h)[i * 16 + cc];
                al[t] = ((const half8*)xs_l)[i * 16 + cc];
            }
            const int tbase = (nc * 4 + dc) * 1024;
            #pragma unroll
            for (int nt = 0; nt < 4; ++nt) {
                // B direct from global: 64 lanes tile 1 KB (16 codes x 32 dims)
                int ui = tbase + (wv * 64 + nt * 16 + l15) * 4 + quad;
                U4H8 tbh, tbl;
                tbh.u = gh4[ui];
                tbl.u = gl4[ui];
                half8 bh = tbh.h, bl = tbl.h;
                #pragma unroll
                for (int t = 0; t < 4; ++t) {
                    acc[t][nt] = __builtin_amdgcn_mfma_f32_16x16x32_f16(ah[t], bh, acc[t][nt], 0, 0, 0);
                    acc[t][nt] = __builtin_amdgcn_mfma_f32_16x16x32_f16(al[t], bh, acc[t][nt], 0, 0, 0);
                    acc[t][nt] = __builtin_amdgcn_mfma_f32_16x16x32_f16(ah[t], bl, acc[t][nt], 0, 0, 0);
                }
            }
        }
        // fold (codes ascend across nc for fixed lane -> strict < keeps first)
        #pragma unroll
        for (int g = 0; g < 4; ++g) {
            int c = nc * 256 + wv * 64 + g * 16 + l15;
            float ee = e2[c];
            #pragma unroll
            for (int t = 0; t < 4; ++t)
                #pragma unroll
                for (int r = 0; r < 4; ++r) {
                    float s = fmaf(-2.f, acc[t][g][r], ee);
                    if (s < bestD[t][r]) { bestD[t][r] = s; bestI[t][r] = c; }
                }
        }
    }

    // reduce across the 16 l15 lanes (different codes, same rows)
    #pragma unroll
    for (int mask = 1; mask <= 8; mask <<= 1) {
        #pragma unroll
        for (int t = 0; t < 4; ++t)
            #pragma unroll
            for (int r = 0; r < 4; ++r) {
                float od = __shfl_xor(bestD[t][r], mask, 64);
                int   oi = __shfl_xor(bestI[t][r], mask, 64);
                if (od < bestD[t][r] || (od == bestD[t][r] && oi < bestI[t][r])) {
                    bestD[t][r] = od; bestI[t][r] = oi;
                }
            }
    }

    // cross-wave reduce via LDS scratch overlaid on xs (dead) -- barrier first
    __syncthreads();
    float* wbD = (float*)smem;
    int*   wbI = (int*)(smem + 1024);
    if (l15 == 0) {
        #pragma unroll
        for (int t = 0; t < 4; ++t)
            #pragma unroll
            for (int r = 0; r < 4; ++r) {
                int m = t * 16 + quad * 4 + r;   // C layout: row=(lane>>4)*4+reg
                wbD[wv * 64 + m] = bestD[t][r];
                wbI[wv * 64 + m] = bestI[t][r];
            }
    }
    __syncthreads();
    if (tid < 64) {
        float bd = wbD[tid]; int bi = wbI[tid];
        #pragma unroll
        for (int w = 1; w < 4; ++w) {
            float od = wbD[w * 64 + tid]; int oi = wbI[w * 64 + tid];
            if (od < bd || (od == bd && oi < bi)) { bd = od; bi = oi; }
        }
        out[IDX_OFF + n0 + tid] = (float)bi;
    }
}

// ---------------------------------------------------------------------------
#define DC 8
// k_ema3: LDS-privatized segment sums -> partials in the Q region of d_out.
// 512 blocks = 32 batches x 16 d-chunks.
__global__ __launch_bounds__(256) void k_ema3(const float* __restrict__ z,
                                              float* __restrict__ out) {
    __shared__ float acc[DC][K];
    __shared__ float cnt[K];

    const int tid = threadIdx.x;
    const int dchunk = blockIdx.x & 15;
    const int b      = blockIdx.x >> 4;
    const int d0 = dchunk * DC;
    const bool doCnt = (dchunk == 0);

    for (int i = tid; i < DC * K; i += 256) ((float*)acc)[i] = 0.f;
    if (doCnt) for (int i = tid; i < K; i += 256) cnt[i] = 0.f;
    __syncthreads();

    const float* zb  = z + b * ZSTRIDE_B;
    const float* idp = out + IDX_OFF + b * HW;
    for (int t = 0; t < HW; t += 1024) {
        const int p = t + 4 * tid;
        int k0 = (int)idp[p + 0];
        int k1 = (int)idp[p + 1];
        int k2 = (int)idp[p + 2];
        int k3 = (int)idp[p + 3];
        if (doCnt) {
            atomicAdd(&cnt[k0], 1.f); atomicAdd(&cnt[k1], 1.f);
            atomicAdd(&cnt[k2], 1.f); atomicAdd(&cnt[k3], 1.f);
        }
        #pragma unroll
        for (int d = 0; d < DC; ++d) {
            float4 zv = *(const float4*)(zb + (d0 + d) * HW + p);
            atomicAdd(&acc[d][k0], zv.x);
            atomicAdd(&acc[d][k1], zv.y);
            atomicAdd(&acc[d][k2], zv.z);
            atomicAdd(&acc[d][k3], zv.w);
        }
    }
    __syncthreads();

    float* pp = out + QS_PART + (size_t)blockIdx.x * (DC * K);
    for (int i = tid; i < DC * K / 4; i += 256)
        ((float4*)pp)[i] = ((const float4*)acc)[i];
    if (doCnt) for (int i = tid; i < K; i += 256) out[QS_CNT + b * K + i] = cnt[i];
}

// k_emared: esum[d][k] = sum over 32 batch-partials (coalesced, no atomics).
__global__ __launch_bounds__(256) void k_emared(const float* __restrict__ out,
                                                float* __restrict__ esum) {
    int id = blockIdx.x * 256 + threadIdx.x;   // 65536 cells
    int d = id >> 9, k = id & 511;
    int dchunk = d >> 3, dd = d & 7;
    const float* p = out + QS_PART + dchunk * (DC * K) + dd * K + k;
    float s = 0.f;
    #pragma unroll 8
    for (int b = 0; b < 32; ++b) s += p[(size_t)b * 16 * DC * K];
    esum[id] = s;
}

// ---------------------------------------------------------------------------
// k_final1: ncs + n (single block, reads cnt partials from Q-scratch).
__global__ __launch_bounds__(512) void k_final1(const float* __restrict__ outR,
                                                const float* __restrict__ cs_in,
                                                float* __restrict__ out,
                                                float* __restrict__ nOut) {
    __shared__ float red[512];
    int k = threadIdx.x;
    float e = 0.f;
    #pragma unroll 8
    for (int b = 0; b < 32; ++b) e += outR[QS_CNT + b * K + k];
    float ncs = fmaf(cs_in[k], 0.99f, 0.01f * e);
    out[NCS_OFF + k] = ncs;
    red[k] = ncs;
    __syncthreads();
    for (int s = 256; s > 0; s >>= 1) {
        if (k < s) red[k] += red[k + s];
        __syncthreads();
    }
    if (k == 0) nOut[0] = fmaxf(red[0], 1e-5f);
}

// ---------------------------------------------------------------------------
// k_q: quantized output + loss. 2048 blocks x 256 (64 pos each).
__global__ __launch_bounds__(256) void k_q(const float* __restrict__ z,
                                           const float* __restrict__ emb,
                                           float* __restrict__ out,
                                           float* __restrict__ lossAcc) {
    __shared__ int bidx[64];
    __shared__ float wred[4];
    const int tid = threadIdx.x;
    const int n0  = blockIdx.x * 64;
    const int b   = n0 >> 12;
    const int hw0 = n0 & 4095;
    const float* zb = z + b * ZSTRIDE_B + hw0;

    if (tid < 64) bidx[tid] = (int)out[IDX_OFF + n0 + tid];
    __syncthreads();

    float lsum = 0.f;
    #pragma unroll 4
    for (int r = 0; r < 32; ++r) {
        int lin = tid + r * 256;
        int d = lin >> 6, i = lin & 63;
        float q  = emb[d * K + bidx[i]];   // gather within one 2 KB row (L1)
        float zz = zb[d * HW + i];
        out[Q_OFF + b * ZSTRIDE_B + d * HW + hw0 + i] = q;
        float df = q - zz;
        lsum = fmaf(df, df, lsum);
    }
    #pragma unroll
    for (int m = 32; m >= 1; m >>= 1) lsum += __shfl_xor(lsum, m, 64);
    int wv = tid >> 6;
    if ((tid & 63) == 0) wred[wv] = lsum;
    __syncthreads();
    if (tid == 0) atomicAdd(lossAcc, wred[0] + wred[1] + wred[2] + wred[3]);
}

// ---------------------------------------------------------------------------
// k_final2: NEA + NEMB (coalesced) + loss scalar. 64 blocks x 256.
__global__ __launch_bounds__(256) void k_final2(const float* __restrict__ esum,
                                                const float* __restrict__ eavg_in,
                                                const float* __restrict__ nPtr,
                                                const float* __restrict__ lossAcc,
                                                float* __restrict__ out) {
    const float n = nPtr[0];
    #pragma unroll
    for (int c = 0; c < 4; ++c) {
        int id = blockIdx.x * 1024 + c * 256 + threadIdx.x;   // 65536 cells
        int k = id & 511;
        float ncs = out[NCS_OFF + k];
        float cs = (ncs + 1e-5f) / (n + (float)K * 1e-5f) * n;
        float ea = fmaf(eavg_in[id], 0.99f, 0.01f * esum[id]);
        out[NEA_OFF + id] = ea;
        out[NEMB_OFF + id] = ea / cs;
    }
    if (blockIdx.x == 0 && threadIdx.x == 0)
        out[LOSS_OFF] = lossAcc[0] * 1.25f / 16777216.0f;
}

// ---------------------------------------------------------------------------
extern "C" void kernel_launch(void* const* d_in, const int* in_sizes, int n_in,
                              void* d_out, int out_size, void* d_ws, size_t ws_size,
                              hipStream_t stream) {
    const float* z     = (const float*)d_in[0];
    const float* emb   = (const float*)d_in[1];
    const float* cs_in = (const float*)d_in[2];
    const float* eavg  = (const float*)d_in[3];
    float* out = (float*)d_out;
    float* wsF = (float*)d_ws;

    // ws layout (266 KB total -- proven-safe footprint):
    float* e2   = wsF + 0;          // 512
    float* loss = wsF + 512;        // 1
    float* nSc  = wsF + 513;        // 1
    u16*   ehi  = (u16*)(wsF + 1024);   // 65536 f16
    u16*   elo  = (u16*)(wsF + 33792);  // 65536 f16
    float* esum = wsF + 1024;           // overlays ehi/elo after k_assign

    hipMemsetAsync(loss, 0, sizeof(float), stream);

    k_prep<<<256, 256, 0, stream>>>(emb, ehi, elo);
    k_e2<<<2, 256, 0, stream>>>(emb, e2);
    k_assign<<<NPOS / 64, 256, 0, stream>>>(z, (const uint4*)ehi,
                                            (const uint4*)elo, e2, out);
    k_ema3<<<512, 256, 0, stream>>>(z, out);          // partials -> Q-scratch
    k_emared<<<256, 256, 0, stream>>>(out, esum);     // reclaims ehi/elo region
    k_final1<<<1, 512, 0, stream>>>(out, cs_in, out, nSc);
    k_q<<<NPOS / 64, 256, 0, stream>>>(z, emb, out, loss);  // overwrites Q-scratch
    k_final2<<<64, 256, 0, stream>>>(esum, eavg, nSc, loss, out);
}